// Round 2
// baseline (304.304 us; speedup 1.0000x reference)
//
#include <hip/hip_runtime.h>
#include <hip/hip_bf16.h>

// Problem constants
#define NB 4
#define NT 4096
#define NE 1024
#define ND 128
// log2(e) / sqrt(128): folded into Wq at prep so attention uses exp2 directly.
#define QSCALE 0.12751741f

typedef unsigned u32x4 __attribute__((ext_vector_type(4)));
typedef float f32x4 __attribute__((ext_vector_type(4)));
typedef float f32x16 __attribute__((ext_vector_type(16)));
typedef __bf16 bf16x8 __attribute__((ext_vector_type(8)));
typedef unsigned short u16;

__device__ __forceinline__ unsigned cvt_pk_bf16(float lo, float hi) {
  unsigned r;
  asm("v_cvt_pk_bf16_f32 %0, %1, %2" : "=v"(r) : "v"(lo), "v"(hi));
  return r;
}
__device__ __forceinline__ void permswap(unsigned& a, unsigned& b) {
  // a' = {a.lo, b.lo}; b' = {a.hi, b.hi}
  asm("v_permlane32_swap_b32 %0, %1" : "+v"(a), "+v"(b));
}
__device__ __forceinline__ u16 f2bf(float f) {  // RNE f32->bf16
  unsigned x = __float_as_uint(f);
  x += 0x7fffu + ((x >> 16) & 1u);
  return (u16)(x >> 16);
}
__device__ __forceinline__ f32x16 mfma32(bf16x8 a, bf16x8 b, f32x16 c) {
  return __builtin_amdgcn_mfma_f32_32x32x16_bf16(a, b, c, 0, 0, 0);
}
__device__ __forceinline__ bf16x8 ldb(const u16* p) {
  return *reinterpret_cast<const bf16x8*>(p);
}

// ---------------- Kernel 0: W -> WT bf16 [3][128 d][1024 e], Wq scaled ----
__global__ void ah_prep(const float* __restrict__ Wq, const float* __restrict__ Wk,
                        const float* __restrict__ Wv, u16* __restrict__ wt) {
  const int g = blockIdx.x * 256 + threadIdx.x;   // 49152 threads, 8 e each
  const int m = g >> 14;            // /16384
  const int r = g & 16383;
  const int d = r >> 7;
  const int ec = r & 127;
  const float* W = (m == 0) ? Wq : (m == 1) ? Wk : Wv;
  const float s = (m == 0) ? QSCALE : 1.0f;
  unsigned o[4];
#pragma unroll
  for (int i = 0; i < 4; ++i) {
    u16 a = f2bf(W[(size_t)(ec * 8 + 2 * i) * ND + d] * s);
    u16 b = f2bf(W[(size_t)(ec * 8 + 2 * i + 1) * ND + d] * s);
    o[i] = (unsigned)a | ((unsigned)b << 16);
  }
  u32x4 v; v[0] = o[0]; v[1] = o[1]; v[2] = o[2]; v[3] = o[3];
  *reinterpret_cast<u32x4*>(wt + (size_t)m * NE * ND + (size_t)d * NE + ec * 8) = v;
}

// ---------------- Kernel 1: QKV projection ---------------------------------
// mat 0: Q bf16 [16384][128] (scale folded in WT); mat 1: K; mat 2: V^T [4][128][4096]
__global__ __launch_bounds__(256, 2) void ah_proj(
    const float* __restrict__ X, const u16* __restrict__ wt,
    u16* __restrict__ qb, u16* __restrict__ kb, u16* __restrict__ vtb) {
  const int bid = blockIdx.x;
  const int mat = bid % 3;
  const int mtile = bid / 3;            // 0..127
  const int row0 = mtile * 128;
  const int tid = threadIdx.x;
  const int w = tid >> 6;
  const int lane = tid & 63;
  const int l31 = lane & 31;
  const int h = lane >> 5;

  const u16* wmat = wt + (size_t)mat * NE * ND;   // [d][e]
  const int rw = row0 + w * 32;
  const float* xrow = X + (size_t)(rw + l31) * NE + h * 8;

  f32x16 acc[4] = {};

#pragma unroll 2
  for (int e0 = 0; e0 < NE; e0 += 16) {
    f32x4 x0 = *reinterpret_cast<const f32x4*>(xrow + e0);
    f32x4 x1 = *reinterpret_cast<const f32x4*>(xrow + e0 + 4);
    u32x4 xw;
    xw[0] = cvt_pk_bf16(x0[0], x0[1]);
    xw[1] = cvt_pk_bf16(x0[2], x0[3]);
    xw[2] = cvt_pk_bf16(x1[0], x1[1]);
    xw[3] = cvt_pk_bf16(x1[2], x1[3]);
    bf16x8 xf = __builtin_bit_cast(bf16x8, xw);
    const u16* wrow = wmat + e0 + h * 8;
    if (mat < 2) {
#pragma unroll
      for (int d0 = 0; d0 < 4; ++d0) {
        bf16x8 wf = ldb(wrow + (size_t)(d0 * 32 + l31) * NE);
        acc[d0] = mfma32(xf, wf, acc[d0]);     // D[t][d]
      }
    } else {
#pragma unroll
      for (int d0 = 0; d0 < 4; ++d0) {
        bf16x8 wf = ldb(wrow + (size_t)(d0 * 32 + l31) * NE);
        acc[d0] = mfma32(wf, xf, acc[d0]);     // D[d][t]  (V^T)
      }
    }
  }

  if (mat < 2) {
    u16* dst = (mat == 0) ? qb : kb;
#pragma unroll
    for (int d0 = 0; d0 < 4; ++d0)
#pragma unroll
      for (int r = 0; r < 16; ++r) {
        const int trow = rw + (r & 3) + 8 * (r >> 2) + 4 * h;
        dst[(size_t)trow * ND + d0 * 32 + l31] = f2bf(acc[d0][r]);
      }
  } else {
    const int bb = rw >> 12;
    const int tt = (rw & 4095) + l31;
#pragma unroll
    for (int d0 = 0; d0 < 4; ++d0)
#pragma unroll
      for (int r = 0; r < 16; ++r) {
        const int d = d0 * 32 + (r & 3) + 8 * (r >> 2) + 4 * h;
        vtb[(size_t)bb * ND * NT + (size_t)d * NT + tt] = f2bf(acc[d0][r]);
      }
  }
}

// ---------------- Kernel 2: causal flash attention -------------------------
// Grid: 4 batches x 64 pairs. Block: 4 waves. Each block: q-tiles p and 127-p
// (constant 129 KV-tiles of work). KV tiles split across waves (j = w mod 4),
// independent online-softmax partials, combined via LDS at the end.
__global__ __launch_bounds__(256, 2) void ah_attn(
    const u16* __restrict__ qg, const u16* __restrict__ kg,
    const u16* __restrict__ vtg, float* __restrict__ out) {
  __shared__ float smem_m[4][32];
  __shared__ float smem_l[4][32];
  __shared__ float smem_linv[32];
  __shared__ float smemO[128][33];

  const int bid = blockIdx.x;
  const int b = bid >> 6;
  const int p = bid & 63;
  const int tid = threadIdx.x;
  const int w = tid >> 6;
  const int lane = tid & 63;
  const int l31 = lane & 31;
  const int h = lane >> 5;

  const u16* Qb = qg + (size_t)b * NT * ND;
  const u16* Kb = kg + (size_t)b * NT * ND;
  const u16* VTb = vtg + (size_t)b * ND * NT;
  float* Ob = out + (size_t)b * NT * ND;

  for (int hf = 0; hf < 2; ++hf) {
    const int qt = hf ? (127 - p) : p;
    const int q0 = qt * 32;

    bf16x8 qf[8];
    {
      const u16* qrow = Qb + (size_t)(q0 + l31) * ND + h * 8;
#pragma unroll
      for (int s = 0; s < 8; ++s) qf[s] = ldb(qrow + s * 16);
    }

    float m_run = -1e30f, l_run = 0.f;
    f32x16 ot[4] = {};

    const int ntiles = qt + 1;
    for (int j = w; j < ntiles; j += 4) {
      const int k0 = j * 32;
      f32x16 sa = {};
      const u16* krow = Kb + (size_t)(k0 + l31) * ND + h * 8;
#pragma unroll
      for (int s = 0; s < 8; ++s) sa = mfma32(ldb(krow + s * 16), qf[s], sa);
      // sa[r] = S^T[key=(r&3)+8*(r>>2)+4h][q=l31]  (already log2e/sqrt(d) scaled)
      if (j == qt) {
#pragma unroll
        for (int r = 0; r < 16; ++r) {
          const int kk = (r & 3) + 8 * (r >> 2) + 4 * h;
          if (kk > l31) sa[r] = -1e30f;
        }
      }
      float mt = sa[0];
#pragma unroll
      for (int r = 1; r < 16; ++r) mt = fmaxf(mt, sa[r]);
      mt = fmaxf(mt, __shfl_xor(mt, 32));
      if (__any(mt > m_run + 8.f)) {            // defer-max (T13)
        const float mn = fmaxf(m_run, mt);
        const float f = __builtin_amdgcn_exp2f(m_run - mn);
        l_run *= f;
#pragma unroll
        for (int d0 = 0; d0 < 4; ++d0) ot[d0] *= f;
        m_run = mn;
      }
      float pr[16];
      float ps = 0.f;
#pragma unroll
      for (int r = 0; r < 16; ++r) {
        pr[r] = __builtin_amdgcn_exp2f(sa[r] - m_run);
        ps += pr[r];
      }
      ps += __shfl_xor(ps, 32);
      l_run += ps;
      // P -> bf16 B-fragments (cvt_pk + permlane32_swap, guide-verified pattern)
      unsigned pk[8];
#pragma unroll
      for (int i = 0; i < 8; ++i) pk[i] = cvt_pk_bf16(pr[2 * i], pr[2 * i + 1]);
      permswap(pk[0], pk[2]);
      permswap(pk[1], pk[3]);
      permswap(pk[4], pk[6]);
      permswap(pk[5], pk[7]);
      u32x4 t0, t1;
      t0[0] = pk[0]; t0[1] = pk[1]; t0[2] = pk[2]; t0[3] = pk[3];
      t1[0] = pk[4]; t1[1] = pk[5]; t1[2] = pk[6]; t1[3] = pk[7];
      bf16x8 pf0 = __builtin_bit_cast(bf16x8, t0);
      bf16x8 pf1 = __builtin_bit_cast(bf16x8, t1);
#pragma unroll
      for (int d0 = 0; d0 < 4; ++d0) {
        const u16* vrow = VTb + (size_t)(d0 * 32 + l31) * NT + k0 + h * 8;
        ot[d0] = mfma32(ldb(vrow), pf0, ot[d0]);        // O^T[d][q]
        ot[d0] = mfma32(ldb(vrow + 16), pf1, ot[d0]);
      }
    }

    // ---- cross-wave combine ----
    if (h == 0) { smem_m[w][l31] = m_run; smem_l[w][l31] = l_run; }
    __syncthreads();
    float mstar = smem_m[0][l31];
#pragma unroll
    for (int wv = 1; wv < 4; ++wv) mstar = fmaxf(mstar, smem_m[wv][l31]);
    float lstar = 0.f;
#pragma unroll
    for (int wv = 0; wv < 4; ++wv)
      lstar += smem_l[wv][l31] * __builtin_amdgcn_exp2f(smem_m[wv][l31] - mstar);
    if (tid < 32) smem_linv[tid] = 1.0f / lstar;
    const float fw = __builtin_amdgcn_exp2f(m_run - mstar);
    for (int rnd = 0; rnd < 4; ++rnd) {
      if (w == rnd) {
#pragma unroll
        for (int d0 = 0; d0 < 4; ++d0)
#pragma unroll
          for (int r = 0; r < 16; ++r) {
            const int d = d0 * 32 + (r & 3) + 8 * (r >> 2) + 4 * h;
            const float v = ot[d0][r] * fw;
            if (rnd == 0) smemO[d][l31] = v;
            else smemO[d][l31] += v;
          }
      }
      __syncthreads();
    }
    {
      const int q = tid >> 3;
      const int dbase = (tid & 7) * 16;
      const float linv = smem_linv[q];
      float* orow = Ob + (size_t)(q0 + q) * ND + dbase;
#pragma unroll
      for (int c = 0; c < 4; ++c) {
        f32x4 v4;
#pragma unroll
        for (int e = 0; e < 4; ++e) v4[e] = smemO[dbase + c * 4 + e][q] * linv;
        *reinterpret_cast<f32x4*>(orow + c * 4) = v4;
      }
    }
    __syncthreads();
  }
}

extern "C" void kernel_launch(void* const* d_in, const int* in_sizes, int n_in,
                              void* d_out, int out_size, void* d_ws, size_t ws_size,
                              hipStream_t stream) {
  const float* X = (const float*)d_in[0];
  const float* Wq = (const float*)d_in[1];
  const float* Wk = (const float*)d_in[2];
  const float* Wv = (const float*)d_in[3];
  u16* ws = (u16*)d_ws;
  u16* wt = ws;                         // 3*128*1024            = 393216
  u16* qb = wt + 393216;                // 16384*128             = 2097152
  u16* kb = qb + 2097152;
  u16* vtb = kb + 2097152;              // V^T [4][128][4096]    = 2097152
  float* out = (float*)d_out;

  ah_prep<<<192, 256, 0, stream>>>(Wq, Wk, Wv, wt);
  ah_proj<<<384, 256, 0, stream>>>(X, wt, qb, kb, vtb);
  ah_attn<<<256, 256, 0, stream>>>(qb, kb, vtb, out);
}

// Round 3
// 265.245 us; speedup vs baseline: 1.1473x; 1.1473x over previous
//
#include <hip/hip_runtime.h>
#include <hip/hip_bf16.h>

// Problem constants
#define NB 4
#define NT 4096
#define NE 1024
#define ND 128
// log2(e) / sqrt(128): folded into Wq at prep so attention uses exp2 directly.
#define QSCALE 0.12751741f

typedef unsigned u32x4 __attribute__((ext_vector_type(4)));
typedef float f32x4 __attribute__((ext_vector_type(4)));
typedef float f32x16 __attribute__((ext_vector_type(16)));
typedef __bf16 bf16x8 __attribute__((ext_vector_type(8)));
typedef unsigned short u16;

__device__ __forceinline__ unsigned cvt_pk_bf16(float lo, float hi) {
  unsigned r;
  asm("v_cvt_pk_bf16_f32 %0, %1, %2" : "=v"(r) : "v"(lo), "v"(hi));
  return r;
}
__device__ __forceinline__ void permswap(unsigned& a, unsigned& b) {
  // a' = {a.lo, b.lo}; b' = {a.hi, b.hi}
  asm("v_permlane32_swap_b32 %0, %1" : "+v"(a), "+v"(b));
}
__device__ __forceinline__ u16 f2bf(float f) {  // RNE f32->bf16
  unsigned x = __float_as_uint(f);
  x += 0x7fffu + ((x >> 16) & 1u);
  return (u16)(x >> 16);
}
__device__ __forceinline__ f32x16 mfma32(bf16x8 a, bf16x8 b, f32x16 c) {
  return __builtin_amdgcn_mfma_f32_32x32x16_bf16(a, b, c, 0, 0, 0);
}
__device__ __forceinline__ bf16x8 ldb(const u16* p) {
  return *reinterpret_cast<const bf16x8*>(p);
}
// P(f32x16, C/D layout) -> two bf16x8 B-fragments for PV
__device__ __forceinline__ void pack_pf(const f32x16& pr, bf16x8& f0, bf16x8& f1) {
  unsigned pk[8];
#pragma unroll
  for (int i = 0; i < 8; ++i) pk[i] = cvt_pk_bf16(pr[2 * i], pr[2 * i + 1]);
  permswap(pk[0], pk[2]);
  permswap(pk[1], pk[3]);
  permswap(pk[4], pk[6]);
  permswap(pk[5], pk[7]);
  u32x4 t0, t1;
  t0[0] = pk[0]; t0[1] = pk[1]; t0[2] = pk[2]; t0[3] = pk[3];
  t1[0] = pk[4]; t1[1] = pk[5]; t1[2] = pk[6]; t1[3] = pk[7];
  f0 = __builtin_bit_cast(bf16x8, t0);
  f1 = __builtin_bit_cast(bf16x8, t1);
}

// ---------------- Kernel 0: W[e][d] -> WT bf16 [3][128 d][1024 e] ----------
// LDS transpose, coalesced f32 reads. Wq scaled by QSCALE.
__global__ void ah_prep(const float* __restrict__ Wq, const float* __restrict__ Wk,
                        const float* __restrict__ Wv, u16* __restrict__ wt) {
  const int m = blockIdx.x >> 5;          // 3 mats x 32 tiles (16 e x 2 d)
  const int r = blockIdx.x & 31;
  const int e0 = (r >> 1) * 64;
  const int d0 = (r & 1) * 64;
  const float* W = (m == 0) ? Wq : (m == 1) ? Wk : Wv;
  const float s = (m == 0) ? QSCALE : 1.0f;
  __shared__ u16 lds[64][68];             // [d][e]
  const int t = threadIdx.x;
  const int row = t >> 2;                 // e-row 0..63
  const int c0 = (t & 3) * 16;            // d-col
  const float* src = W + (size_t)(e0 + row) * ND + d0 + c0;
#pragma unroll
  for (int i = 0; i < 16; i += 4) {
    f32x4 v = *reinterpret_cast<const f32x4*>(src + i);
#pragma unroll
    for (int j = 0; j < 4; ++j) lds[c0 + i + j][row] = f2bf(v[j] * s);
  }
  __syncthreads();
  const int d = t >> 2;                   // 0..63
  const int ec = (t & 3) * 16;            // e within 64
  u16* dst = wt + (size_t)m * NE * ND + (size_t)(d0 + d) * NE + e0 + ec;
  u32x4 o0, o1;
#pragma unroll
  for (int j = 0; j < 4; ++j)
    o0[j] = (unsigned)lds[d][ec + 2 * j] | ((unsigned)lds[d][ec + 2 * j + 1] << 16);
#pragma unroll
  for (int j = 0; j < 4; ++j)
    o1[j] = (unsigned)lds[d][ec + 8 + 2 * j] | ((unsigned)lds[d][ec + 8 + 2 * j + 1] << 16);
  *reinterpret_cast<u32x4*>(dst) = o0;
  *reinterpret_cast<u32x4*>(dst + 8) = o1;
}

// ---------------- Kernel 1: fused QKV projection ---------------------------
// 512 blocks x 4 waves. Block = 32 rows; wave w owns d-cols [w*32, w*32+32)
// of ALL THREE mats (one X fragment -> 3 MFMAs; X read once from HBM).
// Q,K stored [t][d]; V stored transposed [b][d][t].
__global__ __launch_bounds__(256, 2) void ah_proj(
    const float* __restrict__ X, const u16* __restrict__ wt,
    u16* __restrict__ qb, u16* __restrict__ kb, u16* __restrict__ vtb) {
  const int row0 = blockIdx.x * 32;
  const int tid = threadIdx.x;
  const int w = tid >> 6;
  const int lane = tid & 63;
  const int l31 = lane & 31;
  const int h = lane >> 5;

  const float* xrow = X + (size_t)(row0 + l31) * NE + h * 8;
  const u16* wpQ = wt + (size_t)(w * 32 + l31) * NE + h * 8;
  const u16* wpK = wpQ + (size_t)NE * ND;
  const u16* wpV = wpK + (size_t)NE * ND;

  f32x16 accQ = {}, accK = {}, accV = {};

#pragma unroll 2
  for (int e0 = 0; e0 < NE; e0 += 16) {
    f32x4 x0 = *reinterpret_cast<const f32x4*>(xrow + e0);
    f32x4 x1 = *reinterpret_cast<const f32x4*>(xrow + e0 + 4);
    u32x4 xw;
    xw[0] = cvt_pk_bf16(x0[0], x0[1]);
    xw[1] = cvt_pk_bf16(x0[2], x0[3]);
    xw[2] = cvt_pk_bf16(x1[0], x1[1]);
    xw[3] = cvt_pk_bf16(x1[2], x1[3]);
    bf16x8 xf = __builtin_bit_cast(bf16x8, xw);
    accQ = mfma32(xf, ldb(wpQ + e0), accQ);   // D[t][d]
    accK = mfma32(xf, ldb(wpK + e0), accK);   // D[t][d]
    accV = mfma32(ldb(wpV + e0), xf, accV);   // D[d][t]  (V^T)
  }

  const int col = w * 32 + l31;
#pragma unroll
  for (int r = 0; r < 16; ++r) {
    const int trow = row0 + (r & 3) + 8 * (r >> 2) + 4 * h;
    qb[(size_t)trow * ND + col] = f2bf(accQ[r]);
    kb[(size_t)trow * ND + col] = f2bf(accK[r]);
  }
  const int bb = row0 >> 12;
  const int tt = (row0 & 4095) + l31;
#pragma unroll
  for (int r = 0; r < 16; ++r) {
    const int d = w * 32 + (r & 3) + 8 * (r >> 2) + 4 * h;
    vtb[(size_t)bb * ND * NT + (size_t)d * NT + tt] = f2bf(accV[r]);
  }
}

// ---------------- Kernel 2: causal flash attention -------------------------
// 512 blocks x 4 waves; one 32-row q-tile per block. Mapping: work-descending
// (big qt first) AND XCD-affine (bid&7 -> XCD; batch = xcd>>1, so each XCD's
// L2 caches one batch's K/V = 2MB). Wave w handles KV tiles j == w (mod 4),
// TWO tiles per iteration for ILP/MLP. Cross-wave combine via LDS.
__global__ __launch_bounds__(256, 2) void ah_attn(
    const u16* __restrict__ qg, const u16* __restrict__ kg,
    const u16* __restrict__ vtg, float* __restrict__ out) {
  __shared__ float smem_m[4][32];
  __shared__ float smem_l[4][32];
  __shared__ float smem_linv[32];
  __shared__ float smemO[128][33];

  const int bid = blockIdx.x;
  const int xcd = bid & 7;
  const int slot = bid >> 3;              // 0..63
  const int b = xcd >> 1;                 // 2 XCDs per batch
  const int qt = 127 - (slot * 2 + (xcd & 1));
  const int q0 = qt * 32;
  const int tid = threadIdx.x;
  const int w = tid >> 6;
  const int lane = tid & 63;
  const int l31 = lane & 31;
  const int h = lane >> 5;

  const u16* Qb = qg + (size_t)b * NT * ND;
  const u16* Kb = kg + (size_t)b * NT * ND;
  const u16* VTb = vtg + (size_t)b * ND * NT;
  float* Ob = out + (size_t)b * NT * ND;

  bf16x8 qf[8];
  {
    const u16* qrow = Qb + (size_t)(q0 + l31) * ND + h * 8;
#pragma unroll
    for (int s = 0; s < 8; ++s) qf[s] = ldb(qrow + s * 16);
  }

  float m_run = -1e30f, l_run = 0.f;
  f32x16 ot[4] = {};

  const int ntiles = qt + 1;
  for (int j0 = w; j0 < ntiles; j0 += 8) {
    const int j1 = j0 + 4;
    const bool has1 = (j1 < ntiles);
    const int k0 = j0 * 32;
    const int k1 = has1 ? j1 * 32 : k0;   // safe addr; results masked below
    f32x16 sa = {}, sb = {};
    const u16* krow0 = Kb + (size_t)(k0 + l31) * ND + h * 8;
    const u16* krow1 = Kb + (size_t)(k1 + l31) * ND + h * 8;
#pragma unroll
    for (int s = 0; s < 8; ++s) {
      sa = mfma32(ldb(krow0 + s * 16), qf[s], sa);
      sb = mfma32(ldb(krow1 + s * 16), qf[s], sb);
    }
    // sa[r] = S^T[key=(r&3)+8*(r>>2)+4h][q=l31] (log2e/sqrt(d) pre-scaled)
    if (j0 == qt) {
#pragma unroll
      for (int r = 0; r < 16; ++r) {
        const int kk = (r & 3) + 8 * (r >> 2) + 4 * h;
        if (kk > l31) sa[r] = -1e30f;
      }
    }
    if (has1) {
      if (j1 == qt) {
#pragma unroll
        for (int r = 0; r < 16; ++r) {
          const int kk = (r & 3) + 8 * (r >> 2) + 4 * h;
          if (kk > l31) sb[r] = -1e30f;
        }
      }
    } else {
#pragma unroll
      for (int r = 0; r < 16; ++r) sb[r] = -1e30f;
    }
    float mt = sa[0];
#pragma unroll
    for (int r = 1; r < 16; ++r) mt = fmaxf(mt, sa[r]);
#pragma unroll
    for (int r = 0; r < 16; ++r) mt = fmaxf(mt, sb[r]);
    mt = fmaxf(mt, __shfl_xor(mt, 32));
    if (__any(mt > m_run + 8.f)) {        // defer-max (T13)
      const float mn = fmaxf(m_run, mt);
      const float f = __builtin_amdgcn_exp2f(m_run - mn);
      l_run *= f;
#pragma unroll
      for (int d0 = 0; d0 < 4; ++d0) ot[d0] *= f;
      m_run = mn;
    }
    float ps = 0.f;
#pragma unroll
    for (int r = 0; r < 16; ++r) {
      sa[r] = __builtin_amdgcn_exp2f(sa[r] - m_run);
      ps += sa[r];
    }
#pragma unroll
    for (int r = 0; r < 16; ++r) {
      sb[r] = __builtin_amdgcn_exp2f(sb[r] - m_run);
      ps += sb[r];
    }
    ps += __shfl_xor(ps, 32);
    l_run += ps;
    bf16x8 pf0a, pf0b, pf1a, pf1b;
    pack_pf(sa, pf0a, pf0b);
    pack_pf(sb, pf1a, pf1b);
#pragma unroll
    for (int d0 = 0; d0 < 4; ++d0) {
      const u16* vrow0 = VTb + (size_t)(d0 * 32 + l31) * NT + k0 + h * 8;
      const u16* vrow1 = VTb + (size_t)(d0 * 32 + l31) * NT + k1 + h * 8;
      ot[d0] = mfma32(ldb(vrow0), pf0a, ot[d0]);        // O^T[d][q]
      ot[d0] = mfma32(ldb(vrow0 + 16), pf0b, ot[d0]);
      ot[d0] = mfma32(ldb(vrow1), pf1a, ot[d0]);
      ot[d0] = mfma32(ldb(vrow1 + 16), pf1b, ot[d0]);
    }
  }

  // ---- cross-wave combine ----
  if (h == 0) { smem_m[w][l31] = m_run; smem_l[w][l31] = l_run; }
  __syncthreads();
  float mstar = smem_m[0][l31];
#pragma unroll
  for (int wv = 1; wv < 4; ++wv) mstar = fmaxf(mstar, smem_m[wv][l31]);
  float lstar = 0.f;
#pragma unroll
  for (int wv = 0; wv < 4; ++wv)
    lstar += smem_l[wv][l31] * __builtin_amdgcn_exp2f(smem_m[wv][l31] - mstar);
  if (tid < 32) smem_linv[tid] = 1.0f / lstar;
  const float fw = __builtin_amdgcn_exp2f(m_run - mstar);
  for (int rnd = 0; rnd < 4; ++rnd) {
    if (w == rnd) {
#pragma unroll
      for (int d0 = 0; d0 < 4; ++d0)
#pragma unroll
        for (int r = 0; r < 16; ++r) {
          const int d = d0 * 32 + (r & 3) + 8 * (r >> 2) + 4 * h;
          const float v = ot[d0][r] * fw;
          if (rnd == 0) smemO[d][l31] = v;
          else smemO[d][l31] += v;
        }
    }
    __syncthreads();
  }
  {
    const int q = tid >> 3;
    const int dbase = (tid & 7) * 16;
    const float linv = smem_linv[q];
    float* orow = Ob + (size_t)(q0 + q) * ND + dbase;
#pragma unroll
    for (int c = 0; c < 4; ++c) {
      f32x4 v4;
#pragma unroll
      for (int e = 0; e < 4; ++e) v4[e] = smemO[dbase + c * 4 + e][q] * linv;
      *reinterpret_cast<f32x4*>(orow + c * 4) = v4;
    }
  }
}

extern "C" void kernel_launch(void* const* d_in, const int* in_sizes, int n_in,
                              void* d_out, int out_size, void* d_ws, size_t ws_size,
                              hipStream_t stream) {
  const float* X = (const float*)d_in[0];
  const float* Wq = (const float*)d_in[1];
  const float* Wk = (const float*)d_in[2];
  const float* Wv = (const float*)d_in[3];
  u16* ws = (u16*)d_ws;
  u16* wt = ws;                         // 3*128*1024            = 393216
  u16* qb = wt + 393216;                // 16384*128             = 2097152
  u16* kb = qb + 2097152;
  u16* vtb = kb + 2097152;              // V^T [4][128][4096]    = 2097152
  float* out = (float*)d_out;

  ah_prep<<<96, 256, 0, stream>>>(Wq, Wk, Wv, wt);
  ah_proj<<<512, 256, 0, stream>>>(X, wt, qb, kb, vtb);
  ah_attn<<<512, 256, 0, stream>>>(qb, kb, vtb, out);
}